// Round 1
// baseline (1538.424 us; speedup 1.0000x reference)
//
#include <hip/hip_runtime.h>

#define BLK 256

// ---------------- graph preprocessing ----------------

__global__ __launch_bounds__(256) void k_init(float* deg, int* cnt, int* fill, int n) {
    int i = blockIdx.x * BLK + threadIdx.x;
    if (i < n) { deg[i] = 1.0f; cnt[i] = 0; fill[i] = 0; }
}

__global__ __launch_bounds__(256) void k_edge_deg(const int* __restrict__ eidx,
                                                  const float* __restrict__ ea,
                                                  float* deg, int* cnt, int E) {
    int e = blockIdx.x * BLK + threadIdx.x;
    if (e >= E) return;
    int d = eidx[E + e];
    atomicAdd(&deg[d], ea[e]);
    atomicAdd(&cnt[d], 1);
}

__global__ __launch_bounds__(256) void k_dinv(const float* __restrict__ deg,
                                              float* dinv, float* selfn, int n) {
    int i = blockIdx.x * BLK + threadIdx.x;
    if (i >= n) return;
    float dg = deg[i];              // >= 1.0 always (self-loop)
    dinv[i]  = rsqrtf(dg);
    selfn[i] = 1.0f / dg;           // dinv^2 = self-loop norm
}

// single-block exclusive scan of cnt[0..n) -> rowptr[0..n]
__global__ __launch_bounds__(256) void k_scan(const int* __restrict__ cnt, int* rowptr, int n) {
    __shared__ int tile[256];
    __shared__ int carry_s;
    int t = threadIdx.x;
    if (t == 0) carry_s = 0;
    __syncthreads();
    for (int base = 0; base < n; base += 256) {
        int i = base + t;
        int v = (i < n) ? cnt[i] : 0;
        tile[t] = v;
        __syncthreads();
        for (int off = 1; off < 256; off <<= 1) {
            int x = (t >= off) ? tile[t - off] : 0;
            __syncthreads();
            tile[t] += x;
            __syncthreads();
        }
        int carry = carry_s;
        if (i < n) rowptr[i] = carry + tile[t] - v;   // exclusive
        __syncthreads();
        if (t == 255) carry_s = carry + tile[255];
        __syncthreads();
    }
    if (t == 0) rowptr[n] = carry_s;
}

__global__ __launch_bounds__(256) void k_fill(const int* __restrict__ eidx,
                                              const float* __restrict__ ea,
                                              const float* __restrict__ dinv,
                                              const int* __restrict__ rowptr,
                                              int* fill, int* csr_src, float* csr_val, int E) {
    int e = blockIdx.x * BLK + threadIdx.x;
    if (e >= E) return;
    int s = eidx[e];
    int d = eidx[E + e];
    int pos = rowptr[d] + atomicAdd(&fill[d], 1);
    csr_src[pos] = s;
    csr_val[pos] = dinv[s] * ea[e] * dinv[d];
}

// ---------------- per-layer GEMM: C[n,FOUT] = A[n,FIN] @ W[FIN,FOUT] ----------------

template <int FIN, int FOUT>
__global__ __launch_bounds__(256) void k_gemm(const float* __restrict__ A,
                                              const float* __restrict__ W,
                                              float* __restrict__ C, int n) {
    constexpr int TM = 4096 / FOUT;            // rows per block: 32 / 64 / 128
    __shared__ float As[TM * FIN];
    const int tid = threadIdx.x;
    const int tx  = tid % (FOUT / 4);          // 4 cols per thread
    const int ty  = tid / (FOUT / 4);          // 4 rows per thread
    const int row0 = blockIdx.x * TM;

    // stage A tile (vectorized, coalesced)
    const int tot4 = TM * FIN / 4;
    for (int i = tid; i < tot4; i += 256) {
        int r  = i / (FIN / 4);
        int c4 = i % (FIN / 4);
        int gr = row0 + r;
        float4 v = make_float4(0.f, 0.f, 0.f, 0.f);
        if (gr < n) v = ((const float4*)(A + (size_t)gr * FIN))[c4];
        ((float4*)As)[i] = v;
    }
    __syncthreads();

    float acc[4][4] = {};
#pragma unroll
    for (int k = 0; k < FIN; ++k) {
        float4 b = *(const float4*)(W + (size_t)k * FOUT + tx * 4);
        float a0 = As[(ty * 4 + 0) * FIN + k];
        float a1 = As[(ty * 4 + 1) * FIN + k];
        float a2 = As[(ty * 4 + 2) * FIN + k];
        float a3 = As[(ty * 4 + 3) * FIN + k];
        acc[0][0] += a0 * b.x; acc[0][1] += a0 * b.y; acc[0][2] += a0 * b.z; acc[0][3] += a0 * b.w;
        acc[1][0] += a1 * b.x; acc[1][1] += a1 * b.y; acc[1][2] += a1 * b.z; acc[1][3] += a1 * b.w;
        acc[2][0] += a2 * b.x; acc[2][1] += a2 * b.y; acc[2][2] += a2 * b.z; acc[2][3] += a2 * b.w;
        acc[3][0] += a3 * b.x; acc[3][1] += a3 * b.y; acc[3][2] += a3 * b.z; acc[3][3] += a3 * b.w;
    }

#pragma unroll
    for (int r = 0; r < 4; ++r) {
        int gr = row0 + ty * 4 + r;
        if (gr < n) {
            float4 o = make_float4(acc[r][0], acc[r][1], acc[r][2], acc[r][3]);
            *(float4*)(C + (size_t)gr * FOUT + tx * 4) = o;
        }
    }
}

// ---------------- aggregation: out[i] = selfn[i]*H[i] + sum_e csr_val*H[csr_src] + b, (relu) ----------------

template <int FOUT, bool RELU>
__global__ __launch_bounds__(256) void k_agg(const float* __restrict__ H,
                                             const float* __restrict__ selfn,
                                             const int* __restrict__ rowptr,
                                             const int* __restrict__ csr_src,
                                             const float* __restrict__ csr_val,
                                             const float* __restrict__ bias,
                                             float* __restrict__ out, int n) {
    constexpr int NPW = (FOUT <= 32) ? 2 : 1;      // nodes per wave
    const int wave = threadIdx.x >> 6;
    const int lane = threadIdx.x & 63;
    const int node = blockIdx.x * (4 * NPW) + wave * NPW + ((NPW == 2) ? (lane >> 5) : 0);
    const int f    = (NPW == 2) ? (lane & 31) : lane;
    if (node >= n) return;

    constexpr int NF = (FOUT == 128) ? 2 : 1;      // features per lane
    const float sn = selfn[node];
    float acc0 = sn * H[(size_t)node * FOUT + f];
    float acc1 = 0.f;
    if (NF == 2) acc1 = sn * H[(size_t)node * FOUT + f + 64];

    const int e0 = rowptr[node], e1 = rowptr[node + 1];
    for (int e = e0; e < e1; ++e) {
        int   s = csr_src[e];
        float v = csr_val[e];
        acc0 += v * H[(size_t)s * FOUT + f];
        if (NF == 2) acc1 += v * H[(size_t)s * FOUT + f + 64];
    }

    acc0 += bias[f];
    if (RELU) acc0 = fmaxf(acc0, 0.f);
    out[(size_t)node * FOUT + f] = acc0;
    if (NF == 2) {
        acc1 += bias[f + 64];
        if (RELU) acc1 = fmaxf(acc1, 0.f);
        out[(size_t)node * FOUT + f + 64] = acc1;
    }
}

// ---------------- launch ----------------

extern "C" void kernel_launch(void* const* d_in, const int* in_sizes, int n_in,
                              void* d_out, int out_size, void* d_ws, size_t ws_size,
                              hipStream_t stream) {
    const float* x    = (const float*)d_in[0];
    const int*   eidx = (const int*)d_in[1];     // [2][E] (harness delivers integer as int32)
    const float* ea   = (const float*)d_in[2];
    const float* W1   = (const float*)d_in[3];
    const float* b1   = (const float*)d_in[4];
    const float* W2   = (const float*)d_in[5];
    const float* b2   = (const float*)d_in[6];
    const float* W3   = (const float*)d_in[7];
    const float* b3   = (const float*)d_in[8];

    const int N = in_sizes[0] / 128;
    const int E = in_sizes[2];

    // workspace carve-up (256B aligned)
    char*  base = (char*)d_ws;
    size_t off  = 0;
    auto carve = [&](size_t nbytes) -> void* {
        void* p = base + off;
        off = (off + nbytes + 255) & ~(size_t)255;
        return p;
    };
    float* deg     = (float*)carve((size_t)N * 4);
    float* dinv    = (float*)carve((size_t)N * 4);
    float* selfn   = (float*)carve((size_t)N * 4);
    int*   cnt     = (int*)  carve((size_t)N * 4);
    int*   fill    = (int*)  carve((size_t)N * 4);
    int*   rowptr  = (int*)  carve((size_t)(N + 1) * 4);
    int*   csr_src = (int*)  carve((size_t)E * 4);
    float* csr_val = (float*)carve((size_t)E * 4);
    float* bufA    = (float*)carve((size_t)N * 128 * 4);
    float* bufB    = (float*)carve((size_t)N * 128 * 4);
    (void)ws_size;

    const int gN = (N + BLK - 1) / BLK;
    const int gE = (E + BLK - 1) / BLK;

    k_init<<<gN, BLK, 0, stream>>>(deg, cnt, fill, N);
    k_edge_deg<<<gE, BLK, 0, stream>>>(eidx, ea, deg, cnt, E);
    k_dinv<<<gN, BLK, 0, stream>>>(deg, dinv, selfn, N);
    k_scan<<<1, BLK, 0, stream>>>(cnt, rowptr, N);
    k_fill<<<gE, BLK, 0, stream>>>(eidx, ea, dinv, rowptr, fill, csr_src, csr_val, E);

    // layer 1: 128 -> 128, relu
    k_gemm<128, 128><<<(N + 31) / 32, BLK, 0, stream>>>(x, W1, bufA, N);
    k_agg<128, true><<<(N + 3) / 4, BLK, 0, stream>>>(bufA, selfn, rowptr, csr_src, csr_val, b1, bufB, N);

    // layer 2: 128 -> 64, relu
    k_gemm<128, 64><<<(N + 63) / 64, BLK, 0, stream>>>(bufB, W2, bufA, N);
    k_agg<64, true><<<(N + 3) / 4, BLK, 0, stream>>>(bufA, selfn, rowptr, csr_src, csr_val, b2, bufB, N);

    // layer 3: 64 -> 32, no relu
    k_gemm<64, 32><<<(N + 127) / 128, BLK, 0, stream>>>(bufB, W3, bufA, N);
    k_agg<32, false><<<(N + 7) / 8, BLK, 0, stream>>>(bufA, selfn, rowptr, csr_src, csr_val, b3, (float*)d_out, N);
}

// Round 2
// 612.362 us; speedup vs baseline: 2.5123x; 2.5123x over previous
//
#include <hip/hip_runtime.h>

#define BLK 256

// ---------------- graph preprocessing ----------------

__global__ __launch_bounds__(256) void k_init(float* deg, int* cnt, int* fill, int n) {
    int i = blockIdx.x * BLK + threadIdx.x;
    if (i < n) { deg[i] = 1.0f; cnt[i] = 0; fill[i] = 0; }
}

__global__ __launch_bounds__(256) void k_edge_deg(const int* __restrict__ eidx,
                                                  const float* __restrict__ ea,
                                                  float* deg, int* cnt, int E) {
    int e = blockIdx.x * BLK + threadIdx.x;
    if (e >= E) return;
    int d = eidx[E + e];
    atomicAdd(&deg[d], ea[e]);
    atomicAdd(&cnt[d], 1);
}

__global__ __launch_bounds__(256) void k_dinv(const float* __restrict__ deg,
                                              float* dinv, float* selfn, int n) {
    int i = blockIdx.x * BLK + threadIdx.x;
    if (i >= n) return;
    float dg = deg[i];              // >= 1.0 always (self-loop)
    dinv[i]  = rsqrtf(dg);
    selfn[i] = 1.0f / dg;           // dinv^2 = self-loop norm
}

// single-block exclusive scan of cnt[0..n) -> rowptr[0..n]
__global__ __launch_bounds__(256) void k_scan(const int* __restrict__ cnt, int* rowptr, int n) {
    __shared__ int tile[256];
    __shared__ int carry_s;
    int t = threadIdx.x;
    if (t == 0) carry_s = 0;
    __syncthreads();
    for (int base = 0; base < n; base += 256) {
        int i = base + t;
        int v = (i < n) ? cnt[i] : 0;
        tile[t] = v;
        __syncthreads();
        for (int off = 1; off < 256; off <<= 1) {
            int x = (t >= off) ? tile[t - off] : 0;
            __syncthreads();
            tile[t] += x;
            __syncthreads();
        }
        int carry = carry_s;
        if (i < n) rowptr[i] = carry + tile[t] - v;   // exclusive
        __syncthreads();
        if (t == 255) carry_s = carry + tile[255];
        __syncthreads();
    }
    if (t == 0) rowptr[n] = carry_s;
}

__global__ __launch_bounds__(256) void k_fill(const int* __restrict__ eidx,
                                              const float* __restrict__ ea,
                                              const float* __restrict__ dinv,
                                              const int* __restrict__ rowptr,
                                              int* fill, int* csr_src, float* csr_val, int E) {
    int e = blockIdx.x * BLK + threadIdx.x;
    if (e >= E) return;
    int s = eidx[e];
    int d = eidx[E + e];
    int pos = rowptr[d] + atomicAdd(&fill[d], 1);
    csr_src[pos] = s;
    csr_val[pos] = dinv[s] * ea[e] * dinv[d];
}

// ---------------- per-layer GEMM: C[n,FOUT] = A[n,FIN] @ W[FIN,FOUT] ----------------

template <int FIN, int FOUT>
__global__ __launch_bounds__(256) void k_gemm(const float* __restrict__ A,
                                              const float* __restrict__ W,
                                              float* __restrict__ C, int n) {
    constexpr int TM = 4096 / FOUT;            // rows per block: 32 / 64 / 128
    __shared__ float As[TM * FIN];
    const int tid = threadIdx.x;
    const int tx  = tid % (FOUT / 4);          // 4 cols per thread
    const int ty  = tid / (FOUT / 4);          // 4 rows per thread
    const int row0 = blockIdx.x * TM;

    // stage A tile (vectorized, coalesced)
    const int tot4 = TM * FIN / 4;
    for (int i = tid; i < tot4; i += 256) {
        int r  = i / (FIN / 4);
        int c4 = i % (FIN / 4);
        int gr = row0 + r;
        float4 v = make_float4(0.f, 0.f, 0.f, 0.f);
        if (gr < n) v = ((const float4*)(A + (size_t)gr * FIN))[c4];
        ((float4*)As)[i] = v;
    }
    __syncthreads();

    float acc[4][4] = {};
    // NOTE: partial unroll only. Full unroll made the compiler hoist all
    // FIN float4 W-loads -> 256 VGPRs + ~650 MB scratch spill traffic
    // (R1 counters: FETCH 887MB/WRITE 678MB vs 26MB logical).
#pragma unroll 8
    for (int k = 0; k < FIN; ++k) {
        float4 b = *(const float4*)(W + (size_t)k * FOUT + tx * 4);
        float a0 = As[(ty * 4 + 0) * FIN + k];
        float a1 = As[(ty * 4 + 1) * FIN + k];
        float a2 = As[(ty * 4 + 2) * FIN + k];
        float a3 = As[(ty * 4 + 3) * FIN + k];
        acc[0][0] += a0 * b.x; acc[0][1] += a0 * b.y; acc[0][2] += a0 * b.z; acc[0][3] += a0 * b.w;
        acc[1][0] += a1 * b.x; acc[1][1] += a1 * b.y; acc[1][2] += a1 * b.z; acc[1][3] += a1 * b.w;
        acc[2][0] += a2 * b.x; acc[2][1] += a2 * b.y; acc[2][2] += a2 * b.z; acc[2][3] += a2 * b.w;
        acc[3][0] += a3 * b.x; acc[3][1] += a3 * b.y; acc[3][2] += a3 * b.z; acc[3][3] += a3 * b.w;
    }

#pragma unroll
    for (int r = 0; r < 4; ++r) {
        int gr = row0 + ty * 4 + r;
        if (gr < n) {
            float4 o = make_float4(acc[r][0], acc[r][1], acc[r][2], acc[r][3]);
            *(float4*)(C + (size_t)gr * FOUT + tx * 4) = o;
        }
    }
}

// ---------------- aggregation: out[i] = selfn[i]*H[i] + sum_e csr_val*H[csr_src] + b, (relu) ----------------

template <int FOUT, bool RELU>
__global__ __launch_bounds__(256) void k_agg(const float* __restrict__ H,
                                             const float* __restrict__ selfn,
                                             const int* __restrict__ rowptr,
                                             const int* __restrict__ csr_src,
                                             const float* __restrict__ csr_val,
                                             const float* __restrict__ bias,
                                             float* __restrict__ out, int n) {
    constexpr int NPW = (FOUT <= 32) ? 2 : 1;      // nodes per wave
    const int wave = threadIdx.x >> 6;
    const int lane = threadIdx.x & 63;
    const int node = blockIdx.x * (4 * NPW) + wave * NPW + ((NPW == 2) ? (lane >> 5) : 0);
    const int f    = (NPW == 2) ? (lane & 31) : lane;
    if (node >= n) return;

    constexpr int NF = (FOUT == 128) ? 2 : 1;      // features per lane
    const float sn = selfn[node];
    float acc0 = sn * H[(size_t)node * FOUT + f];
    float acc1 = 0.f;
    if (NF == 2) acc1 = sn * H[(size_t)node * FOUT + f + 64];

    const int e0 = rowptr[node], e1 = rowptr[node + 1];
    for (int e = e0; e < e1; ++e) {
        int   s = csr_src[e];
        float v = csr_val[e];
        acc0 += v * H[(size_t)s * FOUT + f];
        if (NF == 2) acc1 += v * H[(size_t)s * FOUT + f + 64];
    }

    acc0 += bias[f];
    if (RELU) acc0 = fmaxf(acc0, 0.f);
    out[(size_t)node * FOUT + f] = acc0;
    if (NF == 2) {
        acc1 += bias[f + 64];
        if (RELU) acc1 = fmaxf(acc1, 0.f);
        out[(size_t)node * FOUT + f + 64] = acc1;
    }
}

// ---------------- launch ----------------

extern "C" void kernel_launch(void* const* d_in, const int* in_sizes, int n_in,
                              void* d_out, int out_size, void* d_ws, size_t ws_size,
                              hipStream_t stream) {
    const float* x    = (const float*)d_in[0];
    const int*   eidx = (const int*)d_in[1];     // [2][E] (harness delivers integer as int32)
    const float* ea   = (const float*)d_in[2];
    const float* W1   = (const float*)d_in[3];
    const float* b1   = (const float*)d_in[4];
    const float* W2   = (const float*)d_in[5];
    const float* b2   = (const float*)d_in[6];
    const float* W3   = (const float*)d_in[7];
    const float* b3   = (const float*)d_in[8];

    const int N = in_sizes[0] / 128;
    const int E = in_sizes[2];

    // workspace carve-up (256B aligned)
    char*  base = (char*)d_ws;
    size_t off  = 0;
    auto carve = [&](size_t nbytes) -> void* {
        void* p = base + off;
        off = (off + nbytes + 255) & ~(size_t)255;
        return p;
    };
    float* deg     = (float*)carve((size_t)N * 4);
    float* dinv    = (float*)carve((size_t)N * 4);
    float* selfn   = (float*)carve((size_t)N * 4);
    int*   cnt     = (int*)  carve((size_t)N * 4);
    int*   fill    = (int*)  carve((size_t)N * 4);
    int*   rowptr  = (int*)  carve((size_t)(N + 1) * 4);
    int*   csr_src = (int*)  carve((size_t)E * 4);
    float* csr_val = (float*)carve((size_t)E * 4);
    float* bufA    = (float*)carve((size_t)N * 128 * 4);
    float* bufB    = (float*)carve((size_t)N * 128 * 4);
    (void)ws_size;

    const int gN = (N + BLK - 1) / BLK;
    const int gE = (E + BLK - 1) / BLK;

    k_init<<<gN, BLK, 0, stream>>>(deg, cnt, fill, N);
    k_edge_deg<<<gE, BLK, 0, stream>>>(eidx, ea, deg, cnt, E);
    k_dinv<<<gN, BLK, 0, stream>>>(deg, dinv, selfn, N);
    k_scan<<<1, BLK, 0, stream>>>(cnt, rowptr, N);
    k_fill<<<gE, BLK, 0, stream>>>(eidx, ea, dinv, rowptr, fill, csr_src, csr_val, E);

    // layer 1: 128 -> 128, relu
    k_gemm<128, 128><<<(N + 31) / 32, BLK, 0, stream>>>(x, W1, bufA, N);
    k_agg<128, true><<<(N + 3) / 4, BLK, 0, stream>>>(bufA, selfn, rowptr, csr_src, csr_val, b1, bufB, N);

    // layer 2: 128 -> 64, relu
    k_gemm<128, 64><<<(N + 63) / 64, BLK, 0, stream>>>(bufB, W2, bufA, N);
    k_agg<64, true><<<(N + 3) / 4, BLK, 0, stream>>>(bufA, selfn, rowptr, csr_src, csr_val, b2, bufB, N);

    // layer 3: 64 -> 32, no relu
    k_gemm<64, 32><<<(N + 127) / 128, BLK, 0, stream>>>(bufB, W3, bufA, N);
    k_agg<32, false><<<(N + 7) / 8, BLK, 0, stream>>>(bufA, selfn, rowptr, csr_src, csr_val, b3, (float*)d_out, N);
}

// Round 3
// 409.058 us; speedup vs baseline: 3.7609x; 1.4970x over previous
//
#include <hip/hip_runtime.h>

#define BLK 256

// ---------------- graph preprocessing ----------------

__global__ __launch_bounds__(256) void k_init(float* deg, int* cnt, int* fill, int n) {
    int i = blockIdx.x * BLK + threadIdx.x;
    if (i < n) { deg[i] = 1.0f; cnt[i] = 0; fill[i] = 0; }
}

__global__ __launch_bounds__(256) void k_edge_deg(const int* __restrict__ eidx,
                                                  const float* __restrict__ ea,
                                                  float* deg, int* cnt, int E) {
    int e = blockIdx.x * BLK + threadIdx.x;
    if (e >= E) return;
    int d = eidx[E + e];
    atomicAdd(&deg[d], ea[e]);
    atomicAdd(&cnt[d], 1);
}

__global__ __launch_bounds__(256) void k_dinv(const float* __restrict__ deg,
                                              float* dinv, float* selfn, int n) {
    int i = blockIdx.x * BLK + threadIdx.x;
    if (i >= n) return;
    float dg = deg[i];              // >= 1.0 always (self-loop)
    dinv[i]  = rsqrtf(dg);
    selfn[i] = 1.0f / dg;           // dinv^2 = self-loop norm
}

// ---------------- device-wide exclusive scan (3 passes) ----------------
// R2 post-mortem: single-block serial-tile scan was 214 us (1 CU busy, 255 idle).

// pass 1: per-block local exclusive scan of cnt -> rowptr, block total -> bsum
__global__ __launch_bounds__(256) void k_scan1(const int* __restrict__ cnt,
                                               int* rowptr, int* bsum, int n) {
    __shared__ int tile[256];
    const int t = threadIdx.x;
    const int i = blockIdx.x * 256 + t;
    int v = (i < n) ? cnt[i] : 0;
    tile[t] = v;
    __syncthreads();
    for (int off = 1; off < 256; off <<= 1) {
        int x = (t >= off) ? tile[t - off] : 0;
        __syncthreads();
        tile[t] += x;
        __syncthreads();
    }
    if (i < n) rowptr[i] = tile[t] - v;              // exclusive within block
    if (t == 255) bsum[blockIdx.x] = tile[255];
}

// pass 2: single block scans bsum[nb] in place (nb <= 256), total -> rowptr[n]
__global__ __launch_bounds__(256) void k_scan2(int* bsum, int* rowptr, int nb, int n) {
    __shared__ int tile[256];
    const int t = threadIdx.x;
    int v = (t < nb) ? bsum[t] : 0;
    tile[t] = v;
    __syncthreads();
    for (int off = 1; off < 256; off <<= 1) {
        int x = (t >= off) ? tile[t - off] : 0;
        __syncthreads();
        tile[t] += x;
        __syncthreads();
    }
    if (t < nb) bsum[t] = tile[t] - v;               // exclusive block offsets
    if (t == 255) rowptr[n] = tile[255];             // grand total = E
}

// pass 3: add block offsets
__global__ __launch_bounds__(256) void k_scan3(int* rowptr, const int* __restrict__ bsum, int n) {
    int i = blockIdx.x * 256 + threadIdx.x;
    if (i < n) rowptr[i] += bsum[blockIdx.x];
}

__global__ __launch_bounds__(256) void k_fill(const int* __restrict__ eidx,
                                              const float* __restrict__ ea,
                                              const float* __restrict__ dinv,
                                              const int* __restrict__ rowptr,
                                              int* fill, int* csr_src, float* csr_val, int E) {
    int e = blockIdx.x * BLK + threadIdx.x;
    if (e >= E) return;
    int s = eidx[e];
    int d = eidx[E + e];
    int pos = rowptr[d] + atomicAdd(&fill[d], 1);
    csr_src[pos] = s;
    csr_val[pos] = dinv[s] * ea[e] * dinv[d];
}

// ---------------- per-layer GEMM: C[n,FOUT] = A[n,FIN] @ W[FIN,FOUT] ----------------

template <int FIN, int FOUT>
__global__ __launch_bounds__(256) void k_gemm(const float* __restrict__ A,
                                              const float* __restrict__ W,
                                              float* __restrict__ C, int n) {
    constexpr int TM = 4096 / FOUT;            // rows per block: 32 / 64 / 128
    __shared__ float As[TM * FIN];
    const int tid = threadIdx.x;
    const int tx  = tid % (FOUT / 4);          // 4 cols per thread
    const int ty  = tid / (FOUT / 4);          // 4 rows per thread
    const int row0 = blockIdx.x * TM;

    // stage A tile (vectorized, coalesced)
    const int tot4 = TM * FIN / 4;
    for (int i = tid; i < tot4; i += 256) {
        int r  = i / (FIN / 4);
        int c4 = i % (FIN / 4);
        int gr = row0 + r;
        float4 v = make_float4(0.f, 0.f, 0.f, 0.f);
        if (gr < n) v = ((const float4*)(A + (size_t)gr * FIN))[c4];
        ((float4*)As)[i] = v;
    }
    __syncthreads();

    float acc[4][4] = {};
    // NOTE: partial unroll only. Full unroll made the compiler hoist all
    // FIN float4 W-loads -> 256 VGPRs + ~650 MB scratch spill traffic
    // (R1 counters: FETCH 887MB/WRITE 678MB vs 26MB logical).
#pragma unroll 8
    for (int k = 0; k < FIN; ++k) {
        float4 b = *(const float4*)(W + (size_t)k * FOUT + tx * 4);
        float a0 = As[(ty * 4 + 0) * FIN + k];
        float a1 = As[(ty * 4 + 1) * FIN + k];
        float a2 = As[(ty * 4 + 2) * FIN + k];
        float a3 = As[(ty * 4 + 3) * FIN + k];
        acc[0][0] += a0 * b.x; acc[0][1] += a0 * b.y; acc[0][2] += a0 * b.z; acc[0][3] += a0 * b.w;
        acc[1][0] += a1 * b.x; acc[1][1] += a1 * b.y; acc[1][2] += a1 * b.z; acc[1][3] += a1 * b.w;
        acc[2][0] += a2 * b.x; acc[2][1] += a2 * b.y; acc[2][2] += a2 * b.z; acc[2][3] += a2 * b.w;
        acc[3][0] += a3 * b.x; acc[3][1] += a3 * b.y; acc[3][2] += a3 * b.z; acc[3][3] += a3 * b.w;
    }

#pragma unroll
    for (int r = 0; r < 4; ++r) {
        int gr = row0 + ty * 4 + r;
        if (gr < n) {
            float4 o = make_float4(acc[r][0], acc[r][1], acc[r][2], acc[r][3]);
            *(float4*)(C + (size_t)gr * FOUT + tx * 4) = o;
        }
    }
}

// ---------------- aggregation: out[i] = selfn[i]*H[i] + sum_e csr_val*H[csr_src] + b, (relu) ----------------

template <int FOUT, bool RELU>
__global__ __launch_bounds__(256) void k_agg(const float* __restrict__ H,
                                             const float* __restrict__ selfn,
                                             const int* __restrict__ rowptr,
                                             const int* __restrict__ csr_src,
                                             const float* __restrict__ csr_val,
                                             const float* __restrict__ bias,
                                             float* __restrict__ out, int n) {
    constexpr int NPW = (FOUT <= 32) ? 2 : 1;      // nodes per wave
    const int wave = threadIdx.x >> 6;
    const int lane = threadIdx.x & 63;
    const int node = blockIdx.x * (4 * NPW) + wave * NPW + ((NPW == 2) ? (lane >> 5) : 0);
    const int f    = (NPW == 2) ? (lane & 31) : lane;
    if (node >= n) return;

    constexpr int NF = (FOUT == 128) ? 2 : 1;      // features per lane
    const float sn = selfn[node];
    float acc0 = sn * H[(size_t)node * FOUT + f];
    float acc1 = 0.f;
    if (NF == 2) acc1 = sn * H[(size_t)node * FOUT + f + 64];

    const int e0 = rowptr[node], e1 = rowptr[node + 1];
    for (int e = e0; e < e1; ++e) {
        int   s = csr_src[e];
        float v = csr_val[e];
        acc0 += v * H[(size_t)s * FOUT + f];
        if (NF == 2) acc1 += v * H[(size_t)s * FOUT + f + 64];
    }

    acc0 += bias[f];
    if (RELU) acc0 = fmaxf(acc0, 0.f);
    out[(size_t)node * FOUT + f] = acc0;
    if (NF == 2) {
        acc1 += bias[f + 64];
        if (RELU) acc1 = fmaxf(acc1, 0.f);
        out[(size_t)node * FOUT + f + 64] = acc1;
    }
}

// ---------------- launch ----------------

extern "C" void kernel_launch(void* const* d_in, const int* in_sizes, int n_in,
                              void* d_out, int out_size, void* d_ws, size_t ws_size,
                              hipStream_t stream) {
    const float* x    = (const float*)d_in[0];
    const int*   eidx = (const int*)d_in[1];     // [2][E] (harness delivers integer as int32)
    const float* ea   = (const float*)d_in[2];
    const float* W1   = (const float*)d_in[3];
    const float* b1   = (const float*)d_in[4];
    const float* W2   = (const float*)d_in[5];
    const float* b2   = (const float*)d_in[6];
    const float* W3   = (const float*)d_in[7];
    const float* b3   = (const float*)d_in[8];

    const int N = in_sizes[0] / 128;
    const int E = in_sizes[2];

    // workspace carve-up (256B aligned)
    char*  base = (char*)d_ws;
    size_t off  = 0;
    auto carve = [&](size_t nbytes) -> void* {
        void* p = base + off;
        off = (off + nbytes + 255) & ~(size_t)255;
        return p;
    };
    float* deg     = (float*)carve((size_t)N * 4);
    float* dinv    = (float*)carve((size_t)N * 4);
    float* selfn   = (float*)carve((size_t)N * 4);
    int*   cnt     = (int*)  carve((size_t)N * 4);
    int*   fill    = (int*)  carve((size_t)N * 4);
    int*   rowptr  = (int*)  carve((size_t)(N + 1) * 4);
    int*   bsum    = (int*)  carve((size_t)256 * 4);
    int*   csr_src = (int*)  carve((size_t)E * 4);
    float* csr_val = (float*)carve((size_t)E * 4);
    float* bufA    = (float*)carve((size_t)N * 128 * 4);
    float* bufB    = (float*)carve((size_t)N * 128 * 4);
    (void)ws_size;

    const int gN = (N + BLK - 1) / BLK;   // 196 blocks for N=50000 (fits k_scan2's <=256)
    const int gE = (E + BLK - 1) / BLK;

    k_init<<<gN, BLK, 0, stream>>>(deg, cnt, fill, N);
    k_edge_deg<<<gE, BLK, 0, stream>>>(eidx, ea, deg, cnt, E);
    k_dinv<<<gN, BLK, 0, stream>>>(deg, dinv, selfn, N);
    k_scan1<<<gN, BLK, 0, stream>>>(cnt, rowptr, bsum, N);
    k_scan2<<<1, BLK, 0, stream>>>(bsum, rowptr, gN, N);
    k_scan3<<<gN, BLK, 0, stream>>>(rowptr, bsum, N);
    k_fill<<<gE, BLK, 0, stream>>>(eidx, ea, dinv, rowptr, fill, csr_src, csr_val, E);

    // layer 1: 128 -> 128, relu
    k_gemm<128, 128><<<(N + 31) / 32, BLK, 0, stream>>>(x, W1, bufA, N);
    k_agg<128, true><<<(N + 3) / 4, BLK, 0, stream>>>(bufA, selfn, rowptr, csr_src, csr_val, b1, bufB, N);

    // layer 2: 128 -> 64, relu
    k_gemm<128, 64><<<(N + 63) / 64, BLK, 0, stream>>>(bufB, W2, bufA, N);
    k_agg<64, true><<<(N + 3) / 4, BLK, 0, stream>>>(bufA, selfn, rowptr, csr_src, csr_val, b2, bufB, N);

    // layer 3: 64 -> 32, no relu
    k_gemm<64, 32><<<(N + 127) / 128, BLK, 0, stream>>>(bufB, W3, bufA, N);
    k_agg<32, false><<<(N + 7) / 8, BLK, 0, stream>>>(bufA, selfn, rowptr, csr_src, csr_val, b3, (float*)d_out, N);
}

// Round 4
// 355.809 us; speedup vs baseline: 4.3237x; 1.1497x over previous
//
#include <hip/hip_runtime.h>
#include <hip/hip_bf16.h>

#define BLK 256

typedef unsigned short ushort_t;
typedef unsigned int uint_t;

static __device__ __forceinline__ float bf2f(ushort_t u) {
    return __uint_as_float((uint_t)u << 16);
}
static __device__ __forceinline__ ushort_t f2bf(float f) {
    __hip_bfloat16 h = __float2bfloat16(f);   // RNE
    return *reinterpret_cast<ushort_t*>(&h);
}

// ---------------- graph preprocessing ----------------

__global__ __launch_bounds__(256) void k_init(float* deg, int* cnt, int* fill, int n) {
    int i = blockIdx.x * BLK + threadIdx.x;
    if (i < n) { deg[i] = 1.0f; cnt[i] = 0; fill[i] = 0; }
}

__global__ __launch_bounds__(256) void k_edge_deg(const int* __restrict__ eidx,
                                                  const float* __restrict__ ea,
                                                  float* deg, int* cnt, int E) {
    int e = blockIdx.x * BLK + threadIdx.x;
    if (e >= E) return;
    int d = eidx[E + e];
    atomicAdd(&deg[d], ea[e]);
    atomicAdd(&cnt[d], 1);
}

__global__ __launch_bounds__(256) void k_dinv(const float* __restrict__ deg,
                                              float* dinv, float* selfn, int n) {
    int i = blockIdx.x * BLK + threadIdx.x;
    if (i >= n) return;
    float dg = deg[i];              // >= 1.0 always (self-loop)
    dinv[i]  = rsqrtf(dg);
    selfn[i] = 1.0f / dg;           // dinv^2 = self-loop norm
}

// ---------------- device-wide exclusive scan (3 passes) ----------------

__global__ __launch_bounds__(256) void k_scan1(const int* __restrict__ cnt,
                                               int* rowptr, int* bsum, int n) {
    __shared__ int tile[256];
    const int t = threadIdx.x;
    const int i = blockIdx.x * 256 + t;
    int v = (i < n) ? cnt[i] : 0;
    tile[t] = v;
    __syncthreads();
    for (int off = 1; off < 256; off <<= 1) {
        int x = (t >= off) ? tile[t - off] : 0;
        __syncthreads();
        tile[t] += x;
        __syncthreads();
    }
    if (i < n) rowptr[i] = tile[t] - v;              // exclusive within block
    if (t == 255) bsum[blockIdx.x] = tile[255];
}

__global__ __launch_bounds__(256) void k_scan2(int* bsum, int* rowptr, int nb, int n) {
    __shared__ int tile[256];
    const int t = threadIdx.x;
    int v = (t < nb) ? bsum[t] : 0;
    tile[t] = v;
    __syncthreads();
    for (int off = 1; off < 256; off <<= 1) {
        int x = (t >= off) ? tile[t - off] : 0;
        __syncthreads();
        tile[t] += x;
        __syncthreads();
    }
    if (t < nb) bsum[t] = tile[t] - v;               // exclusive block offsets
    if (t == 255) rowptr[n] = tile[255];             // grand total = E
}

__global__ __launch_bounds__(256) void k_scan3(int* rowptr, const int* __restrict__ bsum, int n) {
    int i = blockIdx.x * 256 + threadIdx.x;
    if (i < n) rowptr[i] += bsum[blockIdx.x];
}

__global__ __launch_bounds__(256) void k_fill(const int* __restrict__ eidx,
                                              const float* __restrict__ ea,
                                              const float* __restrict__ dinv,
                                              const int* __restrict__ rowptr,
                                              int* fill, int* csr_src, float* csr_val, int E) {
    int e = blockIdx.x * BLK + threadIdx.x;
    if (e >= E) return;
    int s = eidx[e];
    int d = eidx[E + e];
    int pos = rowptr[d] + atomicAdd(&fill[d], 1);
    csr_src[pos] = s;
    csr_val[pos] = dinv[s] * ea[e] * dinv[d];
}

// ---------------- per-layer GEMM: C[n,FOUT](bf16) = A[n,FIN](f32) @ W[FIN,FOUT] ----------------

template <int FIN, int FOUT>
__global__ __launch_bounds__(256) void k_gemm(const float* __restrict__ A,
                                              const float* __restrict__ W,
                                              __hip_bfloat16* __restrict__ C, int n) {
    constexpr int TM = 4096 / FOUT;            // rows per block: 32 / 64 / 128
    __shared__ float As[TM * FIN];
    const int tid = threadIdx.x;
    const int tx  = tid % (FOUT / 4);          // 4 cols per thread
    const int ty  = tid / (FOUT / 4);          // 4 rows per thread
    const int row0 = blockIdx.x * TM;

    // stage A tile (vectorized, coalesced)
    const int tot4 = TM * FIN / 4;
    for (int i = tid; i < tot4; i += 256) {
        int r  = i / (FIN / 4);
        int c4 = i % (FIN / 4);
        int gr = row0 + r;
        float4 v = make_float4(0.f, 0.f, 0.f, 0.f);
        if (gr < n) v = ((const float4*)(A + (size_t)gr * FIN))[c4];
        ((float4*)As)[i] = v;
    }
    __syncthreads();

    float acc[4][4] = {};
    // NOTE: partial unroll only. Full unroll hoists all FIN float4 W-loads ->
    // 256 VGPRs + ~650 MB scratch spill traffic (R1 counters).
#pragma unroll 8
    for (int k = 0; k < FIN; ++k) {
        float4 b = *(const float4*)(W + (size_t)k * FOUT + tx * 4);
        float a0 = As[(ty * 4 + 0) * FIN + k];
        float a1 = As[(ty * 4 + 1) * FIN + k];
        float a2 = As[(ty * 4 + 2) * FIN + k];
        float a3 = As[(ty * 4 + 3) * FIN + k];
        acc[0][0] += a0 * b.x; acc[0][1] += a0 * b.y; acc[0][2] += a0 * b.z; acc[0][3] += a0 * b.w;
        acc[1][0] += a1 * b.x; acc[1][1] += a1 * b.y; acc[1][2] += a1 * b.z; acc[1][3] += a1 * b.w;
        acc[2][0] += a2 * b.x; acc[2][1] += a2 * b.y; acc[2][2] += a2 * b.z; acc[2][3] += a2 * b.w;
        acc[3][0] += a3 * b.x; acc[3][1] += a3 * b.y; acc[3][2] += a3 * b.z; acc[3][3] += a3 * b.w;
    }

#pragma unroll
    for (int r = 0; r < 4; ++r) {
        int gr = row0 + ty * 4 + r;
        if (gr < n) {
            ushort4 o = make_ushort4(f2bf(acc[r][0]), f2bf(acc[r][1]),
                                     f2bf(acc[r][2]), f2bf(acc[r][3]));
            *(ushort4*)((ushort_t*)C + (size_t)gr * FOUT + tx * 4) = o;
        }
    }
}

// ---------------- aggregation: out[i] = selfn[i]*H[i] + sum_e csr_val*H[csr_src] + b, (relu) ----
// H is bf16; each lane owns 2 consecutive features (ushort2) -> per-edge gather is one
// contiguous FOUT*2-byte segment. Accumulate f32, write f32.

template <int FOUT, bool RELU>
__global__ __launch_bounds__(256) void k_agg(const ushort_t* __restrict__ H,
                                             const float* __restrict__ selfn,
                                             const int* __restrict__ rowptr,
                                             const int* __restrict__ csr_src,
                                             const float* __restrict__ csr_val,
                                             const float* __restrict__ bias,
                                             float* __restrict__ out, int n) {
    constexpr int LPN = FOUT / 2;          // lanes per node: 64 / 32 / 16
    constexpr int NPW = 64 / LPN;          // nodes per wave: 1 / 2 / 4
    const int wave = threadIdx.x >> 6;
    const int lane = threadIdx.x & 63;
    const int sub  = lane / LPN;
    const int f2   = lane % LPN;           // feature-pair index
    const int node = (blockIdx.x * 4 + wave) * NPW + sub;
    if (node >= n) return;

    const float sn = selfn[node];
    ushort2 hv = *(const ushort2*)(H + (size_t)node * FOUT + 2 * f2);
    float acc0 = sn * bf2f(hv.x);
    float acc1 = sn * bf2f(hv.y);

    const int e0 = rowptr[node], e1 = rowptr[node + 1];
    for (int e = e0; e < e1; ++e) {
        int   s = csr_src[e];
        float v = csr_val[e];
        ushort2 m = *(const ushort2*)(H + (size_t)s * FOUT + 2 * f2);
        acc0 += v * bf2f(m.x);
        acc1 += v * bf2f(m.y);
    }

    acc0 += bias[2 * f2];
    acc1 += bias[2 * f2 + 1];
    if (RELU) { acc0 = fmaxf(acc0, 0.f); acc1 = fmaxf(acc1, 0.f); }
    *(float2*)(out + (size_t)node * FOUT + 2 * f2) = make_float2(acc0, acc1);
}

// ---------------- launch ----------------

extern "C" void kernel_launch(void* const* d_in, const int* in_sizes, int n_in,
                              void* d_out, int out_size, void* d_ws, size_t ws_size,
                              hipStream_t stream) {
    const float* x    = (const float*)d_in[0];
    const int*   eidx = (const int*)d_in[1];
    const float* ea   = (const float*)d_in[2];
    const float* W1   = (const float*)d_in[3];
    const float* b1   = (const float*)d_in[4];
    const float* W2   = (const float*)d_in[5];
    const float* b2   = (const float*)d_in[6];
    const float* W3   = (const float*)d_in[7];
    const float* b3   = (const float*)d_in[8];

    const int N = in_sizes[0] / 128;
    const int E = in_sizes[2];

    char*  base = (char*)d_ws;
    size_t off  = 0;
    auto carve = [&](size_t nbytes) -> void* {
        void* p = base + off;
        off = (off + nbytes + 255) & ~(size_t)255;
        return p;
    };
    float* deg     = (float*)carve((size_t)N * 4);
    float* dinv    = (float*)carve((size_t)N * 4);
    float* selfn   = (float*)carve((size_t)N * 4);
    int*   cnt     = (int*)  carve((size_t)N * 4);
    int*   fill    = (int*)  carve((size_t)N * 4);
    int*   rowptr  = (int*)  carve((size_t)(N + 1) * 4);
    int*   bsum    = (int*)  carve((size_t)256 * 4);
    int*   csr_src = (int*)  carve((size_t)E * 4);
    float* csr_val = (float*)carve((size_t)E * 4);
    ushort_t* bufH = (ushort_t*)carve((size_t)N * 128 * 2);   // bf16 feature table
    float*    bufF = (float*)   carve((size_t)N * 128 * 4);   // f32 agg output
    (void)ws_size;

    const int gN = (N + BLK - 1) / BLK;   // 196 blocks (fits k_scan2's <=256)
    const int gE = (E + BLK - 1) / BLK;

    k_init<<<gN, BLK, 0, stream>>>(deg, cnt, fill, N);
    k_edge_deg<<<gE, BLK, 0, stream>>>(eidx, ea, deg, cnt, E);
    k_dinv<<<gN, BLK, 0, stream>>>(deg, dinv, selfn, N);
    k_scan1<<<gN, BLK, 0, stream>>>(cnt, rowptr, bsum, N);
    k_scan2<<<1, BLK, 0, stream>>>(bsum, rowptr, gN, N);
    k_scan3<<<gN, BLK, 0, stream>>>(rowptr, bsum, N);
    k_fill<<<gE, BLK, 0, stream>>>(eidx, ea, dinv, rowptr, fill, csr_src, csr_val, E);

    // layer 1: 128 -> 128, relu
    k_gemm<128, 128><<<(N + 31) / 32, BLK, 0, stream>>>(x, W1, (__hip_bfloat16*)bufH, N);
    k_agg<128, true><<<(N + 3) / 4, BLK, 0, stream>>>(bufH, selfn, rowptr, csr_src, csr_val, b1, bufF, N);

    // layer 2: 128 -> 64, relu
    k_gemm<128, 64><<<(N + 63) / 64, BLK, 0, stream>>>(bufF, W2, (__hip_bfloat16*)bufH, N);
    k_agg<64, true><<<(N + 7) / 8, BLK, 0, stream>>>(bufH, selfn, rowptr, csr_src, csr_val, b2, bufF, N);

    // layer 3: 64 -> 32, no relu
    k_gemm<64, 32><<<(N + 127) / 128, BLK, 0, stream>>>(bufF, W3, (__hip_bfloat16*)bufH, N);
    k_agg<32, false><<<(N + 15) / 16, BLK, 0, stream>>>(bufH, selfn, rowptr, csr_src, csr_val, b3, (float*)d_out, N);
}

// Round 5
// 274.330 us; speedup vs baseline: 5.6079x; 1.2970x over previous
//
#include <hip/hip_runtime.h>
#include <hip/hip_bf16.h>

#define BLK 256

typedef unsigned short ushort_t;
typedef unsigned int uint_t;

static __device__ __forceinline__ float bf2f(ushort_t u) {
    return __uint_as_float((uint_t)u << 16);
}
static __device__ __forceinline__ ushort_t f2bf(float f) {
    __hip_bfloat16 h = __float2bfloat16(f);   // RNE
    return *reinterpret_cast<ushort_t*>(&h);
}

// ---------------- graph preprocessing ----------------

__global__ __launch_bounds__(256) void k_init(float* deg, int* cnt, int* fill, int n) {
    int i = blockIdx.x * BLK + threadIdx.x;
    if (i < n) { deg[i] = 1.0f; cnt[i] = 0; fill[i] = 0; }
}

__global__ __launch_bounds__(256) void k_edge_deg(const int* __restrict__ eidx,
                                                  const float* __restrict__ ea,
                                                  float* deg, int* cnt, int E) {
    int e = blockIdx.x * BLK + threadIdx.x;
    if (e >= E) return;
    int d = eidx[E + e];
    atomicAdd(&deg[d], ea[e]);
    atomicAdd(&cnt[d], 1);
}

__global__ __launch_bounds__(256) void k_dinv(const float* __restrict__ deg,
                                              float* dinv, float* selfn, int n) {
    int i = blockIdx.x * BLK + threadIdx.x;
    if (i >= n) return;
    float dg = deg[i];              // >= 1.0 always (self-loop)
    dinv[i]  = rsqrtf(dg);
    selfn[i] = 1.0f / dg;           // dinv^2 = self-loop norm
}

// ---------------- device-wide exclusive scan (3 passes) ----------------

__global__ __launch_bounds__(256) void k_scan1(const int* __restrict__ cnt,
                                               int* rowptr, int* bsum, int n) {
    __shared__ int tile[256];
    const int t = threadIdx.x;
    const int i = blockIdx.x * 256 + t;
    int v = (i < n) ? cnt[i] : 0;
    tile[t] = v;
    __syncthreads();
    for (int off = 1; off < 256; off <<= 1) {
        int x = (t >= off) ? tile[t - off] : 0;
        __syncthreads();
        tile[t] += x;
        __syncthreads();
    }
    if (i < n) rowptr[i] = tile[t] - v;              // exclusive within block
    if (t == 255) bsum[blockIdx.x] = tile[255];
}

__global__ __launch_bounds__(256) void k_scan2(int* bsum, int* rowptr, int nb, int n) {
    __shared__ int tile[256];
    const int t = threadIdx.x;
    int v = (t < nb) ? bsum[t] : 0;
    tile[t] = v;
    __syncthreads();
    for (int off = 1; off < 256; off <<= 1) {
        int x = (t >= off) ? tile[t - off] : 0;
        __syncthreads();
        tile[t] += x;
        __syncthreads();
    }
    if (t < nb) bsum[t] = tile[t] - v;               // exclusive block offsets
    if (t == 255) rowptr[n] = tile[255];             // grand total = E
}

__global__ __launch_bounds__(256) void k_scan3(int* rowptr, const int* __restrict__ bsum, int n) {
    int i = blockIdx.x * 256 + threadIdx.x;
    if (i < n) rowptr[i] += bsum[blockIdx.x];
}

__global__ __launch_bounds__(256) void k_fill(const int* __restrict__ eidx,
                                              const float* __restrict__ ea,
                                              const float* __restrict__ dinv,
                                              const int* __restrict__ rowptr,
                                              int* fill, int* csr_src, float* csr_val, int E) {
    int e = blockIdx.x * BLK + threadIdx.x;
    if (e >= E) return;
    int s = eidx[e];
    int d = eidx[E + e];
    int pos = rowptr[d] + atomicAdd(&fill[d], 1);
    csr_src[pos] = s;
    csr_val[pos] = dinv[s] * ea[e] * dinv[d];
}

// ---------------- per-layer GEMM: C[n,FOUT](bf16) = A[n,FIN](f32) @ W[FIN,FOUT] ----------------

template <int FIN, int FOUT>
__global__ __launch_bounds__(256) void k_gemm(const float* __restrict__ A,
                                              const float* __restrict__ W,
                                              __hip_bfloat16* __restrict__ C, int n) {
    constexpr int TM = 4096 / FOUT;            // rows per block: 32 / 64 / 128
    __shared__ float As[TM * FIN];
    const int tid = threadIdx.x;
    const int tx  = tid % (FOUT / 4);          // 4 cols per thread
    const int ty  = tid / (FOUT / 4);          // 4 rows per thread
    const int row0 = blockIdx.x * TM;

    // stage A tile (vectorized, coalesced)
    const int tot4 = TM * FIN / 4;
    for (int i = tid; i < tot4; i += 256) {
        int r  = i / (FIN / 4);
        int c4 = i % (FIN / 4);
        int gr = row0 + r;
        float4 v = make_float4(0.f, 0.f, 0.f, 0.f);
        if (gr < n) v = ((const float4*)(A + (size_t)gr * FIN))[c4];
        ((float4*)As)[i] = v;
    }
    __syncthreads();

    float acc[4][4] = {};
    // NOTE: partial unroll only. Full unroll hoists all FIN float4 W-loads ->
    // 256 VGPRs + ~650 MB scratch spill traffic (R1 counters).
#pragma unroll 8
    for (int k = 0; k < FIN; ++k) {
        float4 b = *(const float4*)(W + (size_t)k * FOUT + tx * 4);
        float a0 = As[(ty * 4 + 0) * FIN + k];
        float a1 = As[(ty * 4 + 1) * FIN + k];
        float a2 = As[(ty * 4 + 2) * FIN + k];
        float a3 = As[(ty * 4 + 3) * FIN + k];
        acc[0][0] += a0 * b.x; acc[0][1] += a0 * b.y; acc[0][2] += a0 * b.z; acc[0][3] += a0 * b.w;
        acc[1][0] += a1 * b.x; acc[1][1] += a1 * b.y; acc[1][2] += a1 * b.z; acc[1][3] += a1 * b.w;
        acc[2][0] += a2 * b.x; acc[2][1] += a2 * b.y; acc[2][2] += a2 * b.z; acc[2][3] += a2 * b.w;
        acc[3][0] += a3 * b.x; acc[3][1] += a3 * b.y; acc[3][2] += a3 * b.z; acc[3][3] += a3 * b.w;
    }

#pragma unroll
    for (int r = 0; r < 4; ++r) {
        int gr = row0 + ty * 4 + r;
        if (gr < n) {
            ushort4 o = make_ushort4(f2bf(acc[r][0]), f2bf(acc[r][1]),
                                     f2bf(acc[r][2]), f2bf(acc[r][3]));
            *(ushort4*)((ushort_t*)C + (size_t)gr * FOUT + tx * 4) = o;
        }
    }
}

// ---------------- aggregation: out[i] = selfn[i]*H[i] + sum_e csr_val*H[csr_src] + b, (relu) ----
// H is bf16; each lane owns 2 consecutive features. Edge loop manually unrolled x8:
// issue 8 independent H-row gathers before consuming any (R4 was latency-bound:
// 1 gather in flight, HBM at 17% while dur stuck at 81 us).

template <int FOUT, bool RELU>
__global__ __launch_bounds__(256) void k_agg(const ushort_t* __restrict__ H,
                                             const float* __restrict__ selfn,
                                             const int* __restrict__ rowptr,
                                             const int* __restrict__ csr_src,
                                             const float* __restrict__ csr_val,
                                             const float* __restrict__ bias,
                                             float* __restrict__ out, int n) {
    constexpr int LPN = FOUT / 2;          // lanes per node: 64 / 32 / 16
    constexpr int NPW = 64 / LPN;          // nodes per wave: 1 / 2 / 4
    const int wave = threadIdx.x >> 6;
    const int lane = threadIdx.x & 63;
    const int sub  = lane / LPN;
    const int f2   = lane % LPN;           // feature-pair index
    const int node = (blockIdx.x * 4 + wave) * NPW + sub;
    if (node >= n) return;

    const ushort_t* __restrict__ Hf = H + 2 * f2;   // lane-fixed column base

    const float sn = selfn[node];
    ushort2 hv = *(const ushort2*)(Hf + (size_t)node * FOUT);
    float acc0 = sn * bf2f(hv.x);
    float acc1 = sn * bf2f(hv.y);

    const int e0 = rowptr[node], e1 = rowptr[node + 1];
    int e = e0;
    for (; e + 8 <= e1; e += 8) {
        int   s0 = csr_src[e+0], s1 = csr_src[e+1], s2 = csr_src[e+2], s3 = csr_src[e+3];
        int   s4 = csr_src[e+4], s5 = csr_src[e+5], s6 = csr_src[e+6], s7 = csr_src[e+7];
        float v0 = csr_val[e+0], v1 = csr_val[e+1], v2 = csr_val[e+2], v3 = csr_val[e+3];
        float v4 = csr_val[e+4], v5 = csr_val[e+5], v6 = csr_val[e+6], v7 = csr_val[e+7];
        ushort2 m0 = *(const ushort2*)(Hf + (size_t)s0 * FOUT);
        ushort2 m1 = *(const ushort2*)(Hf + (size_t)s1 * FOUT);
        ushort2 m2 = *(const ushort2*)(Hf + (size_t)s2 * FOUT);
        ushort2 m3 = *(const ushort2*)(Hf + (size_t)s3 * FOUT);
        ushort2 m4 = *(const ushort2*)(Hf + (size_t)s4 * FOUT);
        ushort2 m5 = *(const ushort2*)(Hf + (size_t)s5 * FOUT);
        ushort2 m6 = *(const ushort2*)(Hf + (size_t)s6 * FOUT);
        ushort2 m7 = *(const ushort2*)(Hf + (size_t)s7 * FOUT);
        acc0 += v0 * bf2f(m0.x); acc1 += v0 * bf2f(m0.y);
        acc0 += v1 * bf2f(m1.x); acc1 += v1 * bf2f(m1.y);
        acc0 += v2 * bf2f(m2.x); acc1 += v2 * bf2f(m2.y);
        acc0 += v3 * bf2f(m3.x); acc1 += v3 * bf2f(m3.y);
        acc0 += v4 * bf2f(m4.x); acc1 += v4 * bf2f(m4.y);
        acc0 += v5 * bf2f(m5.x); acc1 += v5 * bf2f(m5.y);
        acc0 += v6 * bf2f(m6.x); acc1 += v6 * bf2f(m6.y);
        acc0 += v7 * bf2f(m7.x); acc1 += v7 * bf2f(m7.y);
    }
    for (; e + 2 <= e1; e += 2) {
        int   s0 = csr_src[e+0], s1 = csr_src[e+1];
        float v0 = csr_val[e+0], v1 = csr_val[e+1];
        ushort2 m0 = *(const ushort2*)(Hf + (size_t)s0 * FOUT);
        ushort2 m1 = *(const ushort2*)(Hf + (size_t)s1 * FOUT);
        acc0 += v0 * bf2f(m0.x); acc1 += v0 * bf2f(m0.y);
        acc0 += v1 * bf2f(m1.x); acc1 += v1 * bf2f(m1.y);
    }
    if (e < e1) {
        int   s0 = csr_src[e];
        float v0 = csr_val[e];
        ushort2 m0 = *(const ushort2*)(Hf + (size_t)s0 * FOUT);
        acc0 += v0 * bf2f(m0.x); acc1 += v0 * bf2f(m0.y);
    }

    acc0 += bias[2 * f2];
    acc1 += bias[2 * f2 + 1];
    if (RELU) { acc0 = fmaxf(acc0, 0.f); acc1 = fmaxf(acc1, 0.f); }
    *(float2*)(out + (size_t)node * FOUT + 2 * f2) = make_float2(acc0, acc1);
}

// ---------------- launch ----------------

extern "C" void kernel_launch(void* const* d_in, const int* in_sizes, int n_in,
                              void* d_out, int out_size, void* d_ws, size_t ws_size,
                              hipStream_t stream) {
    const float* x    = (const float*)d_in[0];
    const int*   eidx = (const int*)d_in[1];
    const float* ea   = (const float*)d_in[2];
    const float* W1   = (const float*)d_in[3];
    const float* b1   = (const float*)d_in[4];
    const float* W2   = (const float*)d_in[5];
    const float* b2   = (const float*)d_in[6];
    const float* W3   = (const float*)d_in[7];
    const float* b3   = (const float*)d_in[8];

    const int N = in_sizes[0] / 128;
    const int E = in_sizes[2];

    char*  base = (char*)d_ws;
    size_t off  = 0;
    auto carve = [&](size_t nbytes) -> void* {
        void* p = base + off;
        off = (off + nbytes + 255) & ~(size_t)255;
        return p;
    };
    float* deg     = (float*)carve((size_t)N * 4);
    float* dinv    = (float*)carve((size_t)N * 4);
    float* selfn   = (float*)carve((size_t)N * 4);
    int*   cnt     = (int*)  carve((size_t)N * 4);
    int*   fill    = (int*)  carve((size_t)N * 4);
    int*   rowptr  = (int*)  carve((size_t)(N + 1) * 4);
    int*   bsum    = (int*)  carve((size_t)256 * 4);
    int*   csr_src = (int*)  carve((size_t)E * 4);
    float* csr_val = (float*)carve((size_t)E * 4);
    ushort_t* bufH = (ushort_t*)carve((size_t)N * 128 * 2);   // bf16 feature table
    float*    bufF = (float*)   carve((size_t)N * 128 * 4);   // f32 agg output
    (void)ws_size;

    const int gN = (N + BLK - 1) / BLK;   // 196 blocks (fits k_scan2's <=256)
    const int gE = (E + BLK - 1) / BLK;

    k_init<<<gN, BLK, 0, stream>>>(deg, cnt, fill, N);
    k_edge_deg<<<gE, BLK, 0, stream>>>(eidx, ea, deg, cnt, E);
    k_dinv<<<gN, BLK, 0, stream>>>(deg, dinv, selfn, N);
    k_scan1<<<gN, BLK, 0, stream>>>(cnt, rowptr, bsum, N);
    k_scan2<<<1, BLK, 0, stream>>>(bsum, rowptr, gN, N);
    k_scan3<<<gN, BLK, 0, stream>>>(rowptr, bsum, N);
    k_fill<<<gE, BLK, 0, stream>>>(eidx, ea, dinv, rowptr, fill, csr_src, csr_val, E);

    // layer 1: 128 -> 128, relu
    k_gemm<128, 128><<<(N + 31) / 32, BLK, 0, stream>>>(x, W1, (__hip_bfloat16*)bufH, N);
    k_agg<128, true><<<(N + 3) / 4, BLK, 0, stream>>>(bufH, selfn, rowptr, csr_src, csr_val, b1, bufF, N);

    // layer 2: 128 -> 64, relu
    k_gemm<128, 64><<<(N + 63) / 64, BLK, 0, stream>>>(bufF, W2, (__hip_bfloat16*)bufH, N);
    k_agg<64, true><<<(N + 7) / 8, BLK, 0, stream>>>(bufH, selfn, rowptr, csr_src, csr_val, b2, bufF, N);

    // layer 3: 64 -> 32, no relu
    k_gemm<64, 32><<<(N + 127) / 128, BLK, 0, stream>>>(bufF, W3, (__hip_bfloat16*)bufH, N);
    k_agg<32, false><<<(N + 15) / 16, BLK, 0, stream>>>(bufH, selfn, rowptr, csr_src, csr_val, b3, (float*)d_out, N);
}

// Round 6
// 235.819 us; speedup vs baseline: 6.5237x; 1.1633x over previous
//
#include <hip/hip_runtime.h>
#include <hip/hip_bf16.h>

#define BLK 256
#define NPART 8   // partial histograms for degree accumulation

typedef unsigned short ushort_t;
typedef unsigned int uint_t;
typedef unsigned long long ull_t;

static __device__ __forceinline__ float bf2f(ushort_t u) {
    return __uint_as_float((uint_t)u << 16);
}
static __device__ __forceinline__ ushort_t f2bf(float f) {
    __hip_bfloat16 h = __float2bfloat16(f);   // RNE
    return *reinterpret_cast<ushort_t*>(&h);
}

// ---------------- graph preprocessing ----------------
// R5 post-mortem: k_edge_deg (2x800k random atomics into 200KB) was 75us,
// atomic-contention bound. Now: ONE packed u64 atomic per edge
// (count in bits [40..63], fixed-point sum of ea in bits [0..39]),
// spread over NPART partial histograms to cut per-line contention.

__global__ __launch_bounds__(256) void k_init(ull_t* hist, int* fill, int n8, int n) {
    int i = blockIdx.x * BLK + threadIdx.x;
    if (i < n8) hist[i] = 0ull;
    if (i < n) fill[i] = 0;
}

__global__ __launch_bounds__(256) void k_edge_deg(const int* __restrict__ eidx,
                                                  const float* __restrict__ ea,
                                                  ull_t* hist, int N, int E) {
    int e = blockIdx.x * BLK + threadIdx.x;
    if (e >= E) return;
    int d = eidx[E + e];
    ull_t v = (1ull << 40) | (ull_t)(ea[e] * 4294967296.0f);
    atomicAdd(&hist[(size_t)(blockIdx.x & (NPART - 1)) * N + d], v);
}

// merge partials -> cnt, dinv, selfn  (self-loop weight 1.0 included)
__global__ __launch_bounds__(256) void k_dinv(const ull_t* __restrict__ hist,
                                              int* cnt, float* dinv, float* selfn, int n) {
    int i = blockIdx.x * BLK + threadIdx.x;
    if (i >= n) return;
    ull_t s = 0;
#pragma unroll
    for (int p = 0; p < NPART; ++p) s += hist[(size_t)p * n + i];
    int c = (int)(s >> 40);
    float dg = 1.0f + (float)(s & ((1ull << 40) - 1)) * (1.0f / 4294967296.0f);
    cnt[i]   = c;
    dinv[i]  = rsqrtf(dg);
    selfn[i] = 1.0f / dg;
}

// ---------------- device-wide exclusive scan (3 passes) ----------------

__global__ __launch_bounds__(256) void k_scan1(const int* __restrict__ cnt,
                                               int* rowptr, int* bsum, int n) {
    __shared__ int tile[256];
    const int t = threadIdx.x;
    const int i = blockIdx.x * 256 + t;
    int v = (i < n) ? cnt[i] : 0;
    tile[t] = v;
    __syncthreads();
    for (int off = 1; off < 256; off <<= 1) {
        int x = (t >= off) ? tile[t - off] : 0;
        __syncthreads();
        tile[t] += x;
        __syncthreads();
    }
    if (i < n) rowptr[i] = tile[t] - v;              // exclusive within block
    if (t == 255) bsum[blockIdx.x] = tile[255];
}

__global__ __launch_bounds__(256) void k_scan2(int* bsum, int* rowptr, int nb, int n) {
    __shared__ int tile[256];
    const int t = threadIdx.x;
    int v = (t < nb) ? bsum[t] : 0;
    tile[t] = v;
    __syncthreads();
    for (int off = 1; off < 256; off <<= 1) {
        int x = (t >= off) ? tile[t - off] : 0;
        __syncthreads();
        tile[t] += x;
        __syncthreads();
    }
    if (t < nb) bsum[t] = tile[t] - v;               // exclusive block offsets
    if (t == 255) rowptr[n] = tile[255];             // grand total = E
}

__global__ __launch_bounds__(256) void k_scan3(int* rowptr, const int* __restrict__ bsum, int n) {
    int i = blockIdx.x * 256 + threadIdx.x;
    if (i < n) rowptr[i] += bsum[blockIdx.x];
}

__global__ __launch_bounds__(256) void k_fill(const int* __restrict__ eidx,
                                              const float* __restrict__ ea,
                                              const float* __restrict__ dinv,
                                              const int* __restrict__ rowptr,
                                              int* fill, int* csr_src, float* csr_val, int E) {
    int e = blockIdx.x * BLK + threadIdx.x;
    if (e >= E) return;
    int s = eidx[e];
    int d = eidx[E + e];
    int pos = rowptr[d] + atomicAdd(&fill[d], 1);
    csr_src[pos] = s;
    csr_val[pos] = dinv[s] * ea[e] * dinv[d];
}

// ---------------- per-layer GEMM: C[n,FOUT](bf16) = A[n,FIN](f32) @ W[FIN,FOUT] ----------------

template <int FIN, int FOUT>
__global__ __launch_bounds__(256) void k_gemm(const float* __restrict__ A,
                                              const float* __restrict__ W,
                                              __hip_bfloat16* __restrict__ C, int n) {
    constexpr int TM = 4096 / FOUT;            // rows per block: 32 / 64 / 128
    __shared__ float As[TM * FIN];
    const int tid = threadIdx.x;
    const int tx  = tid % (FOUT / 4);          // 4 cols per thread
    const int ty  = tid / (FOUT / 4);          // 4 rows per thread
    const int row0 = blockIdx.x * TM;

    // stage A tile (vectorized, coalesced)
    const int tot4 = TM * FIN / 4;
    for (int i = tid; i < tot4; i += 256) {
        int r  = i / (FIN / 4);
        int c4 = i % (FIN / 4);
        int gr = row0 + r;
        float4 v = make_float4(0.f, 0.f, 0.f, 0.f);
        if (gr < n) v = ((const float4*)(A + (size_t)gr * FIN))[c4];
        ((float4*)As)[i] = v;
    }
    __syncthreads();

    float acc[4][4] = {};
    // NOTE: partial unroll only. Full unroll hoists all FIN float4 W-loads ->
    // 256 VGPRs + ~650 MB scratch spill traffic (R1 counters).
#pragma unroll 8
    for (int k = 0; k < FIN; ++k) {
        float4 b = *(const float4*)(W + (size_t)k * FOUT + tx * 4);
        float a0 = As[(ty * 4 + 0) * FIN + k];
        float a1 = As[(ty * 4 + 1) * FIN + k];
        float a2 = As[(ty * 4 + 2) * FIN + k];
        float a3 = As[(ty * 4 + 3) * FIN + k];
        acc[0][0] += a0 * b.x; acc[0][1] += a0 * b.y; acc[0][2] += a0 * b.z; acc[0][3] += a0 * b.w;
        acc[1][0] += a1 * b.x; acc[1][1] += a1 * b.y; acc[1][2] += a1 * b.z; acc[1][3] += a1 * b.w;
        acc[2][0] += a2 * b.x; acc[2][1] += a2 * b.y; acc[2][2] += a2 * b.z; acc[2][3] += a2 * b.w;
        acc[3][0] += a3 * b.x; acc[3][1] += a3 * b.y; acc[3][2] += a3 * b.z; acc[3][3] += a3 * b.w;
    }

#pragma unroll
    for (int r = 0; r < 4; ++r) {
        int gr = row0 + ty * 4 + r;
        if (gr < n) {
            ushort4 o = make_ushort4(f2bf(acc[r][0]), f2bf(acc[r][1]),
                                     f2bf(acc[r][2]), f2bf(acc[r][3]));
            *(ushort4*)((ushort_t*)C + (size_t)gr * FOUT + tx * 4) = o;
        }
    }
}

// ---------------- aggregation: out[i] = selfn[i]*H[i] + sum_e csr_val*H[csr_src] + b, (relu) ----
// H is bf16; each lane owns 2 consecutive features. Edge loop manually unrolled x8
// (R4 was latency-bound: 1 gather in flight, HBM at 17%).

template <int FOUT, bool RELU>
__global__ __launch_bounds__(256) void k_agg(const ushort_t* __restrict__ H,
                                             const float* __restrict__ selfn,
                                             const int* __restrict__ rowptr,
                                             const int* __restrict__ csr_src,
                                             const float* __restrict__ csr_val,
                                             const float* __restrict__ bias,
                                             float* __restrict__ out, int n) {
    constexpr int LPN = FOUT / 2;          // lanes per node: 64 / 32 / 16
    constexpr int NPW = 64 / LPN;          // nodes per wave: 1 / 2 / 4
    const int wave = threadIdx.x >> 6;
    const int lane = threadIdx.x & 63;
    const int sub  = lane / LPN;
    const int f2   = lane % LPN;           // feature-pair index
    const int node = (blockIdx.x * 4 + wave) * NPW + sub;
    if (node >= n) return;

    const ushort_t* __restrict__ Hf = H + 2 * f2;   // lane-fixed column base

    const float sn = selfn[node];
    ushort2 hv = *(const ushort2*)(Hf + (size_t)node * FOUT);
    float acc0 = sn * bf2f(hv.x);
    float acc1 = sn * bf2f(hv.y);

    const int e0 = rowptr[node], e1 = rowptr[node + 1];
    int e = e0;
    for (; e + 8 <= e1; e += 8) {
        int   s0 = csr_src[e+0], s1 = csr_src[e+1], s2 = csr_src[e+2], s3 = csr_src[e+3];
        int   s4 = csr_src[e+4], s5 = csr_src[e+5], s6 = csr_src[e+6], s7 = csr_src[e+7];
        float v0 = csr_val[e+0], v1 = csr_val[e+1], v2 = csr_val[e+2], v3 = csr_val[e+3];
        float v4 = csr_val[e+4], v5 = csr_val[e+5], v6 = csr_val[e+6], v7 = csr_val[e+7];
        ushort2 m0 = *(const ushort2*)(Hf + (size_t)s0 * FOUT);
        ushort2 m1 = *(const ushort2*)(Hf + (size_t)s1 * FOUT);
        ushort2 m2 = *(const ushort2*)(Hf + (size_t)s2 * FOUT);
        ushort2 m3 = *(const ushort2*)(Hf + (size_t)s3 * FOUT);
        ushort2 m4 = *(const ushort2*)(Hf + (size_t)s4 * FOUT);
        ushort2 m5 = *(const ushort2*)(Hf + (size_t)s5 * FOUT);
        ushort2 m6 = *(const ushort2*)(Hf + (size_t)s6 * FOUT);
        ushort2 m7 = *(const ushort2*)(Hf + (size_t)s7 * FOUT);
        acc0 += v0 * bf2f(m0.x); acc1 += v0 * bf2f(m0.y);
        acc0 += v1 * bf2f(m1.x); acc1 += v1 * bf2f(m1.y);
        acc0 += v2 * bf2f(m2.x); acc1 += v2 * bf2f(m2.y);
        acc0 += v3 * bf2f(m3.x); acc1 += v3 * bf2f(m3.y);
        acc0 += v4 * bf2f(m4.x); acc1 += v4 * bf2f(m4.y);
        acc0 += v5 * bf2f(m5.x); acc1 += v5 * bf2f(m5.y);
        acc0 += v6 * bf2f(m6.x); acc1 += v6 * bf2f(m6.y);
        acc0 += v7 * bf2f(m7.x); acc1 += v7 * bf2f(m7.y);
    }
    for (; e + 2 <= e1; e += 2) {
        int   s0 = csr_src[e+0], s1 = csr_src[e+1];
        float v0 = csr_val[e+0], v1 = csr_val[e+1];
        ushort2 m0 = *(const ushort2*)(Hf + (size_t)s0 * FOUT);
        ushort2 m1 = *(const ushort2*)(Hf + (size_t)s1 * FOUT);
        acc0 += v0 * bf2f(m0.x); acc1 += v0 * bf2f(m0.y);
        acc0 += v1 * bf2f(m1.x); acc1 += v1 * bf2f(m1.y);
    }
    if (e < e1) {
        int   s0 = csr_src[e];
        float v0 = csr_val[e];
        ushort2 m0 = *(const ushort2*)(Hf + (size_t)s0 * FOUT);
        acc0 += v0 * bf2f(m0.x); acc1 += v0 * bf2f(m0.y);
    }

    acc0 += bias[2 * f2];
    acc1 += bias[2 * f2 + 1];
    if (RELU) { acc0 = fmaxf(acc0, 0.f); acc1 = fmaxf(acc1, 0.f); }
    *(float2*)(out + (size_t)node * FOUT + 2 * f2) = make_float2(acc0, acc1);
}

// ---------------- launch ----------------

extern "C" void kernel_launch(void* const* d_in, const int* in_sizes, int n_in,
                              void* d_out, int out_size, void* d_ws, size_t ws_size,
                              hipStream_t stream) {
    const float* x    = (const float*)d_in[0];
    const int*   eidx = (const int*)d_in[1];
    const float* ea   = (const float*)d_in[2];
    const float* W1   = (const float*)d_in[3];
    const float* b1   = (const float*)d_in[4];
    const float* W2   = (const float*)d_in[5];
    const float* b2   = (const float*)d_in[6];
    const float* W3   = (const float*)d_in[7];
    const float* b3   = (const float*)d_in[8];

    const int N = in_sizes[0] / 128;
    const int E = in_sizes[2];

    char*  base = (char*)d_ws;
    size_t off  = 0;
    auto carve = [&](size_t nbytes) -> void* {
        void* p = base + off;
        off = (off + nbytes + 255) & ~(size_t)255;
        return p;
    };
    ull_t* hist    = (ull_t*)carve((size_t)NPART * N * 8);   // packed cnt|deg partials
    float* dinv    = (float*)carve((size_t)N * 4);
    float* selfn   = (float*)carve((size_t)N * 4);
    int*   cnt     = (int*)  carve((size_t)N * 4);
    int*   fill    = (int*)  carve((size_t)N * 4);
    int*   rowptr  = (int*)  carve((size_t)(N + 1) * 4);
    int*   bsum    = (int*)  carve((size_t)256 * 4);
    int*   csr_src = (int*)  carve((size_t)E * 4);
    float* csr_val = (float*)carve((size_t)E * 4);
    ushort_t* bufH = (ushort_t*)carve((size_t)N * 128 * 2);   // bf16 feature table
    float*    bufF = (float*)   carve((size_t)N * 128 * 4);   // f32 agg output
    (void)ws_size;

    const int gN  = (N + BLK - 1) / BLK;   // 196 blocks (fits k_scan2's <=256)
    const int gN8 = (NPART * N + BLK - 1) / BLK;
    const int gE  = (E + BLK - 1) / BLK;

    k_init<<<gN8, BLK, 0, stream>>>(hist, fill, NPART * N, N);
    k_edge_deg<<<gE, BLK, 0, stream>>>(eidx, ea, hist, N, E);
    k_dinv<<<gN, BLK, 0, stream>>>(hist, cnt, dinv, selfn, N);
    k_scan1<<<gN, BLK, 0, stream>>>(cnt, rowptr, bsum, N);
    k_scan2<<<1, BLK, 0, stream>>>(bsum, rowptr, gN, N);
    k_scan3<<<gN, BLK, 0, stream>>>(rowptr, bsum, N);
    k_fill<<<gE, BLK, 0, stream>>>(eidx, ea, dinv, rowptr, fill, csr_src, csr_val, E);

    // layer 1: 128 -> 128, relu
    k_gemm<128, 128><<<(N + 31) / 32, BLK, 0, stream>>>(x, W1, (__hip_bfloat16*)bufH, N);
    k_agg<128, true><<<(N + 3) / 4, BLK, 0, stream>>>(bufH, selfn, rowptr, csr_src, csr_val, b1, bufF, N);

    // layer 2: 128 -> 64, relu
    k_gemm<128, 64><<<(N + 63) / 64, BLK, 0, stream>>>(bufF, W2, (__hip_bfloat16*)bufH, N);
    k_agg<64, true><<<(N + 7) / 8, BLK, 0, stream>>>(bufH, selfn, rowptr, csr_src, csr_val, b2, bufF, N);

    // layer 3: 64 -> 32, no relu
    k_gemm<64, 32><<<(N + 127) / 128, BLK, 0, stream>>>(bufF, W3, (__hip_bfloat16*)bufH, N);
    k_agg<32, false><<<(N + 15) / 16, BLK, 0, stream>>>(bufH, selfn, rowptr, csr_src, csr_val, b3, (float*)d_out, N);
}